// Round 1
// baseline (801.881 us; speedup 1.0000x reference)
//
#include <hip/hip_runtime.h>

// ---------------- prep: transpose/concat weights to [2*DO][DI] ----------------
__global__ void prep_wt_kernel(const float* __restrict__ wl, const float* __restrict__ wr,
                               float* __restrict__ wt, int di, int dout) {
  int i = blockIdx.x * 256 + threadIdx.x;
  int tot = 2 * dout * di;
  if (i >= tot) return;
  int c = i / di, k = i - c * di;
  wt[i] = (c < dout) ? wl[k * dout + c] : wr[k * dout + (c - dout)];
}

// ---------------- CSR build ----------------
__global__ void deg_kernel(const int* __restrict__ dst, int* __restrict__ cnt, int e) {
  int i = blockIdx.x * 256 + threadIdx.x;
  if (i < e) atomicAdd(&cnt[dst[i]], 1);
}

__global__ void invdeg_kernel(const int* __restrict__ cnt, float* __restrict__ invd, int n) {
  int i = blockIdx.x * 256 + threadIdx.x;
  if (i < n) { int c = cnt[i]; invd[i] = c > 0 ? 1.0f / (float)c : 0.0f; }
}

// exclusive scan over (N+1) elements (element i<N = cnt[i], element N = 0)
__global__ void scan1_kernel(const int* __restrict__ cnt, int* __restrict__ off,
                             int* __restrict__ bsum, int nodes) {
  __shared__ int sh[256];
  int tid = threadIdx.x;
  int base = blockIdx.x * 1024 + tid * 4;
  int a0 = (base + 0 < nodes) ? cnt[base + 0] : 0;
  int a1 = (base + 1 < nodes) ? cnt[base + 1] : 0;
  int a2 = (base + 2 < nodes) ? cnt[base + 2] : 0;
  int a3 = (base + 3 < nodes) ? cnt[base + 3] : 0;
  int s3 = a0 + a1 + a2 + a3;
  sh[tid] = s3;
  __syncthreads();
  for (int d = 1; d < 256; d <<= 1) {
    int v = (tid >= d) ? sh[tid - d] : 0;
    __syncthreads();
    sh[tid] += v;
    __syncthreads();
  }
  int excl = sh[tid] - s3;
  if (base + 0 <= nodes) off[base + 0] = excl;
  if (base + 1 <= nodes) off[base + 1] = excl + a0;
  if (base + 2 <= nodes) off[base + 2] = excl + a0 + a1;
  if (base + 3 <= nodes) off[base + 3] = excl + a0 + a1 + a2;
  if (tid == 255) bsum[blockIdx.x] = sh[255];
}

__global__ void scan2_kernel(int* __restrict__ bsum, int nb) {
  __shared__ int sh[128];
  int tid = threadIdx.x;
  int v = (tid < nb) ? bsum[tid] : 0;
  sh[tid] = v;
  __syncthreads();
  for (int d = 1; d < 128; d <<= 1) {
    int u = (tid >= d) ? sh[tid - d] : 0;
    __syncthreads();
    sh[tid] += u;
    __syncthreads();
  }
  if (tid < nb) bsum[tid] = sh[tid] - v;  // exclusive block offsets
}

__global__ void scan3_kernel(int* __restrict__ off, const int* __restrict__ bsum, int ntot) {
  int i = blockIdx.x * 256 + threadIdx.x;
  if (i < ntot) off[i] += bsum[i >> 10];
}

__global__ void sortfill_kernel(const int* __restrict__ src, const int* __restrict__ dst,
                                const int* __restrict__ off, int* __restrict__ cur,
                                int* __restrict__ csr, int e) {
  int i = blockIdx.x * 256 + threadIdx.x;
  if (i < e) {
    int d = dst[i];
    int pos = atomicAdd(&cur[d], 1);
    csr[off[d] + pos] = src[i];
  }
}

// ---------------- fused linear: p = h@Wl, q = h@Wr + b ----------------
// Tile: 64 rows x NC cols (NC = 2*DO padded to mult of 16), 128 threads,
// thread = 8 rows x (NC/16) cols. wt is pre-transposed [NC][DI].
template <int DI, int NC, int NCREAL, int DO, int KC>
__global__ __launch_bounds__(128, 2) void gemm_pq_kernel(
    const float* __restrict__ h, const float* __restrict__ wt, const float* __restrict__ bias,
    float* __restrict__ p, float* __restrict__ q, int n) {
  constexpr int NJ = NC / 16;
  constexpr int KP = KC + 4;  // padded row stride (floats); 16B aligned, bank shift 4/row
  constexpr int K4 = KC / 4;
  __shared__ float ht[64 * KP];
  __shared__ float wtile[NC * KP];
  int t = threadIdx.x;
  int n0 = blockIdx.x * 64;
  int c0 = t & 15;
  int rq = t >> 4;  // 0..7
  float acc[NJ][8];
#pragma unroll
  for (int j = 0; j < NJ; ++j)
#pragma unroll
    for (int r = 0; r < 8; ++r) acc[j][r] = 0.f;

  for (int kc = 0; kc < DI; kc += KC) {
    for (int i = t; i < 64 * K4; i += 128) {
      int r = i / K4, k4 = i - r * K4;
      int row = n0 + r;
      if (row >= n) row = n - 1;
      float4 v = *(const float4*)(h + (size_t)row * DI + kc + k4 * 4);
      *(float4*)(ht + r * KP + k4 * 4) = v;
    }
    for (int i = t; i < NC * K4; i += 128) {
      int c = i / K4, k4 = i - c * K4;
      float4 v = make_float4(0.f, 0.f, 0.f, 0.f);
      if (c < NCREAL) v = *(const float4*)(wt + c * DI + kc + k4 * 4);
      *(float4*)(wtile + c * KP + k4 * 4) = v;
    }
    __syncthreads();
    for (int k4 = 0; k4 < K4; ++k4) {
      float4 hh[8];
#pragma unroll
      for (int r = 0; r < 8; ++r) hh[r] = *(const float4*)(ht + (rq + 8 * r) * KP + k4 * 4);
#pragma unroll
      for (int j = 0; j < NJ; ++j) {
        float4 w = *(const float4*)(wtile + (c0 + 16 * j) * KP + k4 * 4);
#pragma unroll
        for (int r = 0; r < 8; ++r)
          acc[j][r] += w.x * hh[r].x + w.y * hh[r].y + w.z * hh[r].z + w.w * hh[r].w;
      }
    }
    __syncthreads();
  }
#pragma unroll
  for (int j = 0; j < NJ; ++j) {
    int c = c0 + 16 * j;
    if (c >= NCREAL) continue;
#pragma unroll
    for (int r = 0; r < 8; ++r) {
      int row = n0 + rq + 8 * r;
      if (row < n) {
        if (c < DO)
          p[(size_t)row * DO + c] = acc[j][r];
        else
          q[(size_t)row * DO + (c - DO)] = acc[j][r] + bias[c - DO];
      }
    }
  }
}

// ---------------- aggregation: out = inv_deg * sum_{e} p[src] + q (+relu) ----------------
template <int DO, bool RELU>
__global__ __launch_bounds__(256) void aggregate4_kernel(
    const float* __restrict__ p, const float* __restrict__ q, const int* __restrict__ off,
    const int* __restrict__ csr, const float* __restrict__ invd, float* __restrict__ ho, int n) {
  constexpr int DOT = DO / 4;  // lanes per node, float4 each
  int t = blockIdx.x * 256 + threadIdx.x;
  int node = t / DOT;
  int c4 = t - node * DOT;
  if (node >= n) return;
  int e0 = off[node], e1 = off[node + 1];
  const float4* p4 = (const float4*)p;
  float4 s = make_float4(0.f, 0.f, 0.f, 0.f);
  for (int e = e0; e < e1; ++e) {
    int sidx = csr[e];
    float4 v = p4[(size_t)sidx * DOT + c4];
    s.x += v.x; s.y += v.y; s.z += v.z; s.w += v.w;
  }
  float id = invd[node];
  float4 qv = ((const float4*)q)[(size_t)node * DOT + c4];
  float4 o;
  o.x = s.x * id + qv.x;
  o.y = s.y * id + qv.y;
  o.z = s.z * id + qv.z;
  o.w = s.w * id + qv.w;
  if (RELU) {
    o.x = fmaxf(o.x, 0.f); o.y = fmaxf(o.y, 0.f);
    o.z = fmaxf(o.z, 0.f); o.w = fmaxf(o.w, 0.f);
  }
  ((float4*)ho)[(size_t)node * DOT + c4] = o;
}

// final layer: DO=5 (team of 8 lanes, 5 active), no relu
__global__ __launch_bounds__(256) void aggregate_last_kernel(
    const float* __restrict__ p, const float* __restrict__ q, const int* __restrict__ off,
    const int* __restrict__ csr, const float* __restrict__ invd, float* __restrict__ ho, int n) {
  int t = blockIdx.x * 256 + threadIdx.x;
  int node = t >> 3;
  int c = t & 7;
  if (node >= n || c >= 5) return;
  int e0 = off[node], e1 = off[node + 1];
  float s = 0.f;
  for (int e = e0; e < e1; ++e) {
    int sidx = csr[e];
    s += p[(size_t)sidx * 5 + c];
  }
  ho[(size_t)node * 5 + c] = s * invd[node] + q[(size_t)node * 5 + c];
}

// ---------------- launch ----------------
extern "C" void kernel_launch(void* const* d_in, const int* in_sizes, int n_in,
                              void* d_out, int out_size, void* d_ws, size_t ws_size,
                              hipStream_t stream) {
  const float* x = (const float*)d_in[0];
  const int* ei = (const int*)d_in[1];
  const int E = in_sizes[1] / 2;
  const int* esrc = ei;
  const int* edst = ei + E;
  const float* W1l = (const float*)d_in[3];
  const float* W1r = (const float*)d_in[4];
  const float* b1 = (const float*)d_in[5];
  const float* W2l = (const float*)d_in[6];
  const float* W2r = (const float*)d_in[7];
  const float* b2 = (const float*)d_in[8];
  const float* W3l = (const float*)d_in[9];
  const float* W3r = (const float*)d_in[10];
  const float* b3 = (const float*)d_in[11];
  const float* W4l = (const float*)d_in[12];
  const float* W4r = (const float*)d_in[13];
  const float* b4 = (const float*)d_in[14];
  const int N = in_sizes[0] / 768;
  float* out = (float*)d_out;
  (void)n_in; (void)out_size; (void)ws_size;

  char* base = (char*)d_ws;
  size_t o = 0;
  auto alloc = [&](size_t bytes) -> void* {
    void* ptr = base + o;
    o = (o + bytes + 255) & ~(size_t)255;
    return ptr;
  };
  int* cnt = (int*)alloc((size_t)N * 4);
  int* cur = (int*)alloc((size_t)N * 4);
  int* off = (int*)alloc((size_t)(N + 1) * 4);
  int* bsum = (int*)alloc(1024);
  int* csr = (int*)alloc((size_t)E * 4);
  float* invd = (float*)alloc((size_t)N * 4);
  float* wt1 = (float*)alloc((size_t)128 * 768 * 4);
  float* wt2 = (float*)alloc((size_t)64 * 64 * 4);
  float* wt3 = (float*)alloc((size_t)32 * 32 * 4);
  float* wt4 = (float*)alloc((size_t)10 * 16 * 4);
  float* A = (float*)alloc((size_t)N * 64 * 4);   // p
  float* B = (float*)alloc((size_t)N * 64 * 4);   // q
  float* C = (float*)alloc((size_t)N * 64 * 4);   // h1 / h3
  float* D = (float*)alloc((size_t)N * 32 * 4);   // h2

  hipMemsetAsync(cnt, 0, (size_t)N * 4, stream);
  hipMemsetAsync(cur, 0, (size_t)N * 4, stream);

  prep_wt_kernel<<<(2 * 64 * 768 + 255) / 256, 256, 0, stream>>>(W1l, W1r, wt1, 768, 64);
  prep_wt_kernel<<<(2 * 32 * 64 + 255) / 256, 256, 0, stream>>>(W2l, W2r, wt2, 64, 32);
  prep_wt_kernel<<<(2 * 16 * 32 + 255) / 256, 256, 0, stream>>>(W3l, W3r, wt3, 32, 16);
  prep_wt_kernel<<<(2 * 5 * 16 + 255) / 256, 256, 0, stream>>>(W4l, W4r, wt4, 16, 5);

  deg_kernel<<<(E + 255) / 256, 256, 0, stream>>>(edst, cnt, E);
  invdeg_kernel<<<(N + 255) / 256, 256, 0, stream>>>(cnt, invd, N);
  const int nb = (N + 1 + 1023) / 1024;  // 98 for N=100000 (<=128)
  scan1_kernel<<<nb, 256, 0, stream>>>(cnt, off, bsum, N);
  scan2_kernel<<<1, 128, 0, stream>>>(bsum, nb);
  scan3_kernel<<<(N + 1 + 255) / 256, 256, 0, stream>>>(off, bsum, N + 1);
  sortfill_kernel<<<(E + 255) / 256, 256, 0, stream>>>(esrc, edst, off, cur, csr, E);

  const int gb = (N + 63) / 64;
  // Layer 1: 768 -> 64
  gemm_pq_kernel<768, 128, 128, 64, 32><<<gb, 128, 0, stream>>>(x, wt1, b1, A, B, N);
  aggregate4_kernel<64, true><<<(N * 16 + 255) / 256, 256, 0, stream>>>(A, B, off, csr, invd, C, N);
  // Layer 2: 64 -> 32
  gemm_pq_kernel<64, 64, 64, 32, 64><<<gb, 128, 0, stream>>>(C, wt2, b2, A, B, N);
  aggregate4_kernel<32, true><<<(N * 8 + 255) / 256, 256, 0, stream>>>(A, B, off, csr, invd, D, N);
  // Layer 3: 32 -> 16
  gemm_pq_kernel<32, 32, 32, 16, 32><<<gb, 128, 0, stream>>>(D, wt3, b3, A, B, N);
  aggregate4_kernel<16, true><<<(N * 4 + 255) / 256, 256, 0, stream>>>(A, B, off, csr, invd, C, N);
  // Layer 4: 16 -> 5 (no relu)
  gemm_pq_kernel<16, 16, 10, 5, 16><<<gb, 128, 0, stream>>>(C, wt4, b4, A, B, N);
  aggregate_last_kernel<<<(N * 8 + 255) / 256, 256, 0, stream>>>(A, B, off, csr, invd, out, N);
}

// Round 2
// 458.335 us; speedup vs baseline: 1.7496x; 1.7496x over previous
//
#include <hip/hip_runtime.h>

using half8 = __attribute__((ext_vector_type(8))) _Float16;
using f32x4 = __attribute__((ext_vector_type(4))) float;

// ---------------- prep: transpose/concat weights to [2*DO][DI] (fp32, layers 2-4) ----
__global__ void prep_wt_kernel(const float* __restrict__ wl, const float* __restrict__ wr,
                               float* __restrict__ wt, int di, int dout) {
  int i = blockIdx.x * 256 + threadIdx.x;
  int tot = 2 * dout * di;
  if (i >= tot) return;
  int c = i / di, k = i - c * di;
  wt[i] = (c < dout) ? wl[k * dout + c] : wr[k * dout + (c - dout)];
}

// ---------------- prep: layer-1 weights -> fp16 [128 cols][768 k] ----------------
__global__ void prep_w16_kernel(const float* __restrict__ wl, const float* __restrict__ wr,
                                _Float16* __restrict__ w16) {
  int i = blockIdx.x * 256 + threadIdx.x;
  if (i >= 128 * 768) return;
  int c = i / 768, k = i - c * 768;
  float v = (c < 64) ? wl[k * 64 + c] : wr[k * 64 + (c - 64)];
  w16[i] = (_Float16)v;
}

// ---------------- CSR build ----------------
__global__ void deg_kernel(const int* __restrict__ dst, int* __restrict__ cnt, int e) {
  int i = blockIdx.x * 256 + threadIdx.x;
  if (i < e) atomicAdd(&cnt[dst[i]], 1);
}

__global__ void invdeg_kernel(const int* __restrict__ cnt, float* __restrict__ invd, int n) {
  int i = blockIdx.x * 256 + threadIdx.x;
  if (i < n) { int c = cnt[i]; invd[i] = c > 0 ? 1.0f / (float)c : 0.0f; }
}

__global__ void scan1_kernel(const int* __restrict__ cnt, int* __restrict__ off,
                             int* __restrict__ bsum, int nodes) {
  __shared__ int sh[256];
  int tid = threadIdx.x;
  int base = blockIdx.x * 1024 + tid * 4;
  int a0 = (base + 0 < nodes) ? cnt[base + 0] : 0;
  int a1 = (base + 1 < nodes) ? cnt[base + 1] : 0;
  int a2 = (base + 2 < nodes) ? cnt[base + 2] : 0;
  int a3 = (base + 3 < nodes) ? cnt[base + 3] : 0;
  int s3 = a0 + a1 + a2 + a3;
  sh[tid] = s3;
  __syncthreads();
  for (int d = 1; d < 256; d <<= 1) {
    int v = (tid >= d) ? sh[tid - d] : 0;
    __syncthreads();
    sh[tid] += v;
    __syncthreads();
  }
  int excl = sh[tid] - s3;
  if (base + 0 <= nodes) off[base + 0] = excl;
  if (base + 1 <= nodes) off[base + 1] = excl + a0;
  if (base + 2 <= nodes) off[base + 2] = excl + a0 + a1;
  if (base + 3 <= nodes) off[base + 3] = excl + a0 + a1 + a2;
  if (tid == 255) bsum[blockIdx.x] = sh[255];
}

__global__ void scan2_kernel(int* __restrict__ bsum, int nb) {
  __shared__ int sh[128];
  int tid = threadIdx.x;
  int v = (tid < nb) ? bsum[tid] : 0;
  sh[tid] = v;
  __syncthreads();
  for (int d = 1; d < 128; d <<= 1) {
    int u = (tid >= d) ? sh[tid - d] : 0;
    __syncthreads();
    sh[tid] += u;
    __syncthreads();
  }
  if (tid < nb) bsum[tid] = sh[tid] - v;
}

__global__ void scan3_kernel(int* __restrict__ off, const int* __restrict__ bsum, int ntot) {
  int i = blockIdx.x * 256 + threadIdx.x;
  if (i < ntot) off[i] += bsum[i >> 10];
}

__global__ void sortfill_kernel(const int* __restrict__ src, const int* __restrict__ dst,
                                const int* __restrict__ off, int* __restrict__ cur,
                                int* __restrict__ csr, int e) {
  int i = blockIdx.x * 256 + threadIdx.x;
  if (i < e) {
    int d = dst[i];
    int pos = atomicAdd(&cur[d], 1);
    csr[off[d] + pos] = src[i];
  }
}

// ---------------- layer-1 MFMA GEMM: p = x@W1l, q = x@W1r + b ----------------
// fp16 hi/lo split of x (2 MFMA passes), fp32 accumulate. No LDS, no barriers.
// Wave = 32 rows x 128 cols (2 m-frags x 8 n-frags). Block = 4 waves = 128 rows.
__global__ __launch_bounds__(256) void gemm1_mfma_kernel(
    const float* __restrict__ x,       // [n][768]
    const _Float16* __restrict__ w16,  // [128][768]  (row c = output col)
    const float* __restrict__ bias,    // [64]
    float* __restrict__ p, float* __restrict__ q, int n) {
  constexpr int DI = 768;
  int wave = threadIdx.x >> 6;
  int lane = threadIdx.x & 63;
  int m0 = blockIdx.x * 128 + wave * 32;
  int lm = lane & 15;
  int lk = lane >> 4;  // k-group 0..3
  int r0 = m0 + lm, r1 = m0 + 16 + lm;
  if (r0 >= n) r0 = n - 1;
  if (r1 >= n) r1 = n - 1;
  const float* xr0 = x + (size_t)r0 * DI + lk * 8;
  const float* xr1 = x + (size_t)r1 * DI + lk * 8;
  const _Float16* wp = w16 + (size_t)lm * DI + lk * 8;

  f32x4 acc[2][8];
#pragma unroll
  for (int mi = 0; mi < 2; ++mi)
#pragma unroll
    for (int ni = 0; ni < 8; ++ni) acc[mi][ni] = (f32x4){0.f, 0.f, 0.f, 0.f};

  for (int kc = 0; kc < DI; kc += 32) {
    // A: 8 fp32 per row-frag per lane (coalesced 128B across the 4 k-groups)
    f32x4 a0a = *(const f32x4*)(xr0 + kc);
    f32x4 a0b = *(const f32x4*)(xr0 + kc + 4);
    f32x4 a1a = *(const f32x4*)(xr1 + kc);
    f32x4 a1b = *(const f32x4*)(xr1 + kc + 4);
    half8 ah0, al0, ah1, al1;
#pragma unroll
    for (int j = 0; j < 4; ++j) {
      _Float16 h;
      h = (_Float16)a0a[j]; ah0[j] = h; al0[j] = (_Float16)(a0a[j] - (float)h);
      h = (_Float16)a0b[j]; ah0[4 + j] = h; al0[4 + j] = (_Float16)(a0b[j] - (float)h);
      h = (_Float16)a1a[j]; ah1[j] = h; al1[j] = (_Float16)(a1a[j] - (float)h);
      h = (_Float16)a1b[j]; ah1[4 + j] = h; al1[4 + j] = (_Float16)(a1b[j] - (float)h);
    }
    // B: 8 col-frags straight from L2 (w16 is 196 KB, L2-resident)
    half8 bf[8];
#pragma unroll
    for (int ni = 0; ni < 8; ++ni)
      bf[ni] = *(const half8*)(wp + (size_t)ni * 16 * DI + kc);
#pragma unroll
    for (int ni = 0; ni < 8; ++ni) {
      acc[0][ni] = __builtin_amdgcn_mfma_f32_16x16x32_f16(ah0, bf[ni], acc[0][ni], 0, 0, 0);
      acc[1][ni] = __builtin_amdgcn_mfma_f32_16x16x32_f16(ah1, bf[ni], acc[1][ni], 0, 0, 0);
    }
#pragma unroll
    for (int ni = 0; ni < 8; ++ni) {
      acc[0][ni] = __builtin_amdgcn_mfma_f32_16x16x32_f16(al0, bf[ni], acc[0][ni], 0, 0, 0);
      acc[1][ni] = __builtin_amdgcn_mfma_f32_16x16x32_f16(al1, bf[ni], acc[1][ni], 0, 0, 0);
    }
  }
  // C/D layout: col = lane&15, row = (lane>>4)*4 + j  [m89-verified]
#pragma unroll
  for (int mi = 0; mi < 2; ++mi)
#pragma unroll
    for (int ni = 0; ni < 8; ++ni) {
      int col = ni * 16 + lm;
#pragma unroll
      for (int j = 0; j < 4; ++j) {
        int row = m0 + mi * 16 + lk * 4 + j;
        if (row < n) {
          float v = acc[mi][ni][j];
          if (col < 64) p[(size_t)row * 64 + col] = v;
          else q[(size_t)row * 64 + (col - 64)] = v + bias[col - 64];
        }
      }
    }
}

// ---------------- fp32 VALU GEMM (layers 2-4) ----------------
template <int DI, int NC, int NCREAL, int DO, int KC>
__global__ __launch_bounds__(128, 2) void gemm_pq_kernel(
    const float* __restrict__ h, const float* __restrict__ wt, const float* __restrict__ bias,
    float* __restrict__ p, float* __restrict__ q, int n) {
  constexpr int NJ = NC / 16;
  constexpr int KP = KC + 4;
  constexpr int K4 = KC / 4;
  __shared__ float ht[64 * KP];
  __shared__ float wtile[NC * KP];
  int t = threadIdx.x;
  int n0 = blockIdx.x * 64;
  int c0 = t & 15;
  int rq = t >> 4;
  float acc[NJ][8];
#pragma unroll
  for (int j = 0; j < NJ; ++j)
#pragma unroll
    for (int r = 0; r < 8; ++r) acc[j][r] = 0.f;

  for (int kc = 0; kc < DI; kc += KC) {
    for (int i = t; i < 64 * K4; i += 128) {
      int r = i / K4, k4 = i - r * K4;
      int row = n0 + r;
      if (row >= n) row = n - 1;
      float4 v = *(const float4*)(h + (size_t)row * DI + kc + k4 * 4);
      *(float4*)(ht + r * KP + k4 * 4) = v;
    }
    for (int i = t; i < NC * K4; i += 128) {
      int c = i / K4, k4 = i - c * K4;
      float4 v = make_float4(0.f, 0.f, 0.f, 0.f);
      if (c < NCREAL) v = *(const float4*)(wt + c * DI + kc + k4 * 4);
      *(float4*)(wtile + c * KP + k4 * 4) = v;
    }
    __syncthreads();
    for (int k4 = 0; k4 < K4; ++k4) {
      float4 hh[8];
#pragma unroll
      for (int r = 0; r < 8; ++r) hh[r] = *(const float4*)(ht + (rq + 8 * r) * KP + k4 * 4);
#pragma unroll
      for (int j = 0; j < NJ; ++j) {
        float4 w = *(const float4*)(wtile + (c0 + 16 * j) * KP + k4 * 4);
#pragma unroll
        for (int r = 0; r < 8; ++r)
          acc[j][r] += w.x * hh[r].x + w.y * hh[r].y + w.z * hh[r].z + w.w * hh[r].w;
      }
    }
    __syncthreads();
  }
#pragma unroll
  for (int j = 0; j < NJ; ++j) {
    int c = c0 + 16 * j;
    if (c >= NCREAL) continue;
#pragma unroll
    for (int r = 0; r < 8; ++r) {
      int row = n0 + rq + 8 * r;
      if (row < n) {
        if (c < DO)
          p[(size_t)row * DO + c] = acc[j][r];
        else
          q[(size_t)row * DO + (c - DO)] = acc[j][r] + bias[c - DO];
      }
    }
  }
}

// ---------------- aggregation ----------------
template <int DO, bool RELU>
__global__ __launch_bounds__(256) void aggregate4_kernel(
    const float* __restrict__ p, const float* __restrict__ q, const int* __restrict__ off,
    const int* __restrict__ csr, const float* __restrict__ invd, float* __restrict__ ho, int n) {
  constexpr int DOT = DO / 4;
  int t = blockIdx.x * 256 + threadIdx.x;
  int node = t / DOT;
  int c4 = t - node * DOT;
  if (node >= n) return;
  int e0 = off[node], e1 = off[node + 1];
  const float4* p4 = (const float4*)p;
  float4 s = make_float4(0.f, 0.f, 0.f, 0.f);
  for (int e = e0; e < e1; ++e) {
    int sidx = csr[e];
    float4 v = p4[(size_t)sidx * DOT + c4];
    s.x += v.x; s.y += v.y; s.z += v.z; s.w += v.w;
  }
  float id = invd[node];
  float4 qv = ((const float4*)q)[(size_t)node * DOT + c4];
  float4 o;
  o.x = s.x * id + qv.x;
  o.y = s.y * id + qv.y;
  o.z = s.z * id + qv.z;
  o.w = s.w * id + qv.w;
  if (RELU) {
    o.x = fmaxf(o.x, 0.f); o.y = fmaxf(o.y, 0.f);
    o.z = fmaxf(o.z, 0.f); o.w = fmaxf(o.w, 0.f);
  }
  ((float4*)ho)[(size_t)node * DOT + c4] = o;
}

__global__ __launch_bounds__(256) void aggregate_last_kernel(
    const float* __restrict__ p, const float* __restrict__ q, const int* __restrict__ off,
    const int* __restrict__ csr, const float* __restrict__ invd, float* __restrict__ ho, int n) {
  int t = blockIdx.x * 256 + threadIdx.x;
  int node = t >> 3;
  int c = t & 7;
  if (node >= n || c >= 5) return;
  int e0 = off[node], e1 = off[node + 1];
  float s = 0.f;
  for (int e = e0; e < e1; ++e) {
    int sidx = csr[e];
    s += p[(size_t)sidx * 5 + c];
  }
  ho[(size_t)node * 5 + c] = s * invd[node] + q[(size_t)node * 5 + c];
}

// ---------------- launch ----------------
extern "C" void kernel_launch(void* const* d_in, const int* in_sizes, int n_in,
                              void* d_out, int out_size, void* d_ws, size_t ws_size,
                              hipStream_t stream) {
  const float* x = (const float*)d_in[0];
  const int* ei = (const int*)d_in[1];
  const int E = in_sizes[1] / 2;
  const int* esrc = ei;
  const int* edst = ei + E;
  const float* W1l = (const float*)d_in[3];
  const float* W1r = (const float*)d_in[4];
  const float* b1 = (const float*)d_in[5];
  const float* W2l = (const float*)d_in[6];
  const float* W2r = (const float*)d_in[7];
  const float* b2 = (const float*)d_in[8];
  const float* W3l = (const float*)d_in[9];
  const float* W3r = (const float*)d_in[10];
  const float* b3 = (const float*)d_in[11];
  const float* W4l = (const float*)d_in[12];
  const float* W4r = (const float*)d_in[13];
  const float* b4 = (const float*)d_in[14];
  const int N = in_sizes[0] / 768;
  float* out = (float*)d_out;
  (void)n_in; (void)out_size; (void)ws_size;

  char* base = (char*)d_ws;
  size_t o = 0;
  auto alloc = [&](size_t bytes) -> void* {
    void* ptr = base + o;
    o = (o + bytes + 255) & ~(size_t)255;
    return ptr;
  };
  int* cnt = (int*)alloc((size_t)N * 4);
  int* cur = (int*)alloc((size_t)N * 4);
  int* off = (int*)alloc((size_t)(N + 1) * 4);
  int* bsum = (int*)alloc(1024);
  int* csr = (int*)alloc((size_t)E * 4);
  float* invd = (float*)alloc((size_t)N * 4);
  _Float16* w16 = (_Float16*)alloc((size_t)128 * 768 * 2);
  float* wt2 = (float*)alloc((size_t)64 * 64 * 4);
  float* wt3 = (float*)alloc((size_t)32 * 32 * 4);
  float* wt4 = (float*)alloc((size_t)10 * 16 * 4);
  float* A = (float*)alloc((size_t)N * 64 * 4);   // p
  float* B = (float*)alloc((size_t)N * 64 * 4);   // q
  float* C = (float*)alloc((size_t)N * 64 * 4);   // h1 / h3
  float* D = (float*)alloc((size_t)N * 32 * 4);   // h2

  hipMemsetAsync(cnt, 0, (size_t)N * 4, stream);
  hipMemsetAsync(cur, 0, (size_t)N * 4, stream);

  prep_w16_kernel<<<(128 * 768 + 255) / 256, 256, 0, stream>>>(W1l, W1r, w16);
  prep_wt_kernel<<<(2 * 32 * 64 + 255) / 256, 256, 0, stream>>>(W2l, W2r, wt2, 64, 32);
  prep_wt_kernel<<<(2 * 16 * 32 + 255) / 256, 256, 0, stream>>>(W3l, W3r, wt3, 32, 16);
  prep_wt_kernel<<<(2 * 5 * 16 + 255) / 256, 256, 0, stream>>>(W4l, W4r, wt4, 16, 5);

  deg_kernel<<<(E + 255) / 256, 256, 0, stream>>>(edst, cnt, E);
  invdeg_kernel<<<(N + 255) / 256, 256, 0, stream>>>(cnt, invd, N);
  const int nb = (N + 1 + 1023) / 1024;
  scan1_kernel<<<nb, 256, 0, stream>>>(cnt, off, bsum, N);
  scan2_kernel<<<1, 128, 0, stream>>>(bsum, nb);
  scan3_kernel<<<(N + 1 + 255) / 256, 256, 0, stream>>>(off, bsum, N + 1);
  sortfill_kernel<<<(E + 255) / 256, 256, 0, stream>>>(esrc, edst, off, cur, csr, E);

  // Layer 1: 768 -> 64 (MFMA fp16 hi/lo split)
  gemm1_mfma_kernel<<<(N + 127) / 128, 256, 0, stream>>>(x, w16, b1, A, B, N);
  aggregate4_kernel<64, true><<<(N * 16 + 255) / 256, 256, 0, stream>>>(A, B, off, csr, invd, C, N);
  // Layer 2: 64 -> 32
  const int gb = (N + 63) / 64;
  gemm_pq_kernel<64, 64, 64, 32, 64><<<gb, 128, 0, stream>>>(C, wt2, b2, A, B, N);
  aggregate4_kernel<32, true><<<(N * 8 + 255) / 256, 256, 0, stream>>>(A, B, off, csr, invd, D, N);
  // Layer 3: 32 -> 16
  gemm_pq_kernel<32, 32, 32, 16, 32><<<gb, 128, 0, stream>>>(D, wt3, b3, A, B, N);
  aggregate4_kernel<16, true><<<(N * 4 + 255) / 256, 256, 0, stream>>>(A, B, off, csr, invd, C, N);
  // Layer 4: 16 -> 5 (no relu)
  gemm_pq_kernel<16, 16, 10, 5, 16><<<gb, 128, 0, stream>>>(C, wt4, b4, A, B, N);
  aggregate_last_kernel<<<(N * 8 + 255) / 256, 256, 0, stream>>>(A, B, off, csr, invd, out, N);
}

// Round 3
// 342.376 us; speedup vs baseline: 2.3421x; 1.3387x over previous
//
#include <hip/hip_runtime.h>

using half8 = __attribute__((ext_vector_type(8))) _Float16;
using f32x4 = __attribute__((ext_vector_type(4))) float;

// ---------------- prep: layer-1 weights -> fp16 [128 cols][768 k] ----------------
__global__ void prep_w16_kernel(const float* __restrict__ wl, const float* __restrict__ wr,
                                _Float16* __restrict__ w16) {
  int i = blockIdx.x * 256 + threadIdx.x;
  if (i >= 128 * 768) return;
  int c = i / 768, k = i - c * 768;
  float v = (c < 64) ? wl[k * 64 + c] : wr[k * 64 + (c - 64)];
  w16[i] = (_Float16)v;
}

// generic small-layer prep: w16 [ncp][dip], zero-padded in k (k>=di) and cols (c>=2*dout)
__global__ void prep_w16s_kernel(const float* __restrict__ wl, const float* __restrict__ wr,
                                 _Float16* __restrict__ w16, int di, int dip, int dout, int ncp) {
  int i = blockIdx.x * 256 + threadIdx.x;
  if (i >= ncp * dip) return;
  int c = i / dip, k = i - c * dip;
  float v = 0.f;
  if (k < di && c < 2 * dout) v = (c < dout) ? wl[k * dout + c] : wr[k * dout + (c - dout)];
  w16[i] = (_Float16)v;
}

// ---------------- CSR build ----------------
__global__ void deg_kernel(const int* __restrict__ dst, int* __restrict__ cnt, int e) {
  int i = blockIdx.x * 256 + threadIdx.x;
  if (i < e) atomicAdd(&cnt[dst[i]], 1);
}

__global__ void invdeg_kernel(const int* __restrict__ cnt, float* __restrict__ invd, int n) {
  int i = blockIdx.x * 256 + threadIdx.x;
  if (i < n) { int c = cnt[i]; invd[i] = c > 0 ? 1.0f / (float)c : 0.0f; }
}

__global__ void scan1_kernel(const int* __restrict__ cnt, int* __restrict__ off,
                             int* __restrict__ bsum, int nodes) {
  __shared__ int sh[256];
  int tid = threadIdx.x;
  int base = blockIdx.x * 1024 + tid * 4;
  int a0 = (base + 0 < nodes) ? cnt[base + 0] : 0;
  int a1 = (base + 1 < nodes) ? cnt[base + 1] : 0;
  int a2 = (base + 2 < nodes) ? cnt[base + 2] : 0;
  int a3 = (base + 3 < nodes) ? cnt[base + 3] : 0;
  int s3 = a0 + a1 + a2 + a3;
  sh[tid] = s3;
  __syncthreads();
  for (int d = 1; d < 256; d <<= 1) {
    int v = (tid >= d) ? sh[tid - d] : 0;
    __syncthreads();
    sh[tid] += v;
    __syncthreads();
  }
  int excl = sh[tid] - s3;
  if (base + 0 <= nodes) off[base + 0] = excl;
  if (base + 1 <= nodes) off[base + 1] = excl + a0;
  if (base + 2 <= nodes) off[base + 2] = excl + a0 + a1;
  if (base + 3 <= nodes) off[base + 3] = excl + a0 + a1 + a2;
  if (tid == 255) bsum[blockIdx.x] = sh[255];
}

__global__ void scan2_kernel(int* __restrict__ bsum, int nb) {
  __shared__ int sh[128];
  int tid = threadIdx.x;
  int v = (tid < nb) ? bsum[tid] : 0;
  sh[tid] = v;
  __syncthreads();
  for (int d = 1; d < 128; d <<= 1) {
    int u = (tid >= d) ? sh[tid - d] : 0;
    __syncthreads();
    sh[tid] += u;
    __syncthreads();
  }
  if (tid < nb) bsum[tid] = sh[tid] - v;
}

__global__ void scan3_kernel(int* __restrict__ off, const int* __restrict__ bsum, int ntot) {
  int i = blockIdx.x * 256 + threadIdx.x;
  if (i < ntot) off[i] += bsum[i >> 10];
}

__global__ void sortfill_kernel(const int* __restrict__ src, const int* __restrict__ dst,
                                const int* __restrict__ off, int* __restrict__ cur,
                                int* __restrict__ csr, int e) {
  int i = blockIdx.x * 256 + threadIdx.x;
  if (i < e) {
    int d = dst[i];
    int pos = atomicAdd(&cur[d], 1);
    csr[off[d] + pos] = src[i];
  }
}

// ---------------- layer-1 MFMA GEMM: p = x@W1l, q = x@W1r + b  (fp16 out) -------
// 1 wave per block, 32 rows x 128 cols. Single fp16 pass, fp32 accum.
// Register double-buffer: prefetch next 32-k chunk (x from HBM, B from L2).
__global__ __launch_bounds__(64, 2) void gemm1_mfma_kernel(
    const float* __restrict__ x,       // [n][768]
    const _Float16* __restrict__ w16,  // [128][768]
    const float* __restrict__ bias,    // [64]
    _Float16* __restrict__ p, _Float16* __restrict__ q, int n) {
  constexpr int DI = 768;
  int lane = threadIdx.x;
  int m0 = blockIdx.x * 32;
  int lm = lane & 15;
  int lk = lane >> 4;
  int r0 = m0 + lm; if (r0 >= n) r0 = n - 1;
  int r1 = m0 + 16 + lm; if (r1 >= n) r1 = n - 1;
  const float* xr0 = x + (size_t)r0 * DI + lk * 8;
  const float* xr1 = x + (size_t)r1 * DI + lk * 8;
  const _Float16* wp = w16 + (size_t)lm * DI + lk * 8;

  f32x4 acc[2][8];
#pragma unroll
  for (int mi = 0; mi < 2; ++mi)
#pragma unroll
    for (int ni = 0; ni < 8; ++ni) acc[mi][ni] = (f32x4){0.f, 0.f, 0.f, 0.f};

  f32x4 xA[4], xB[4];
  half8 bA[8], bB[8];

  xA[0] = *(const f32x4*)(xr0 + 0);
  xA[1] = *(const f32x4*)(xr0 + 4);
  xA[2] = *(const f32x4*)(xr1 + 0);
  xA[3] = *(const f32x4*)(xr1 + 4);
#pragma unroll
  for (int ni = 0; ni < 8; ++ni) bA[ni] = *(const half8*)(wp + (size_t)ni * 16 * DI);

  for (int kc = 0; kc < DI; kc += 64) {
    // prefetch odd chunk
    xB[0] = *(const f32x4*)(xr0 + kc + 32);
    xB[1] = *(const f32x4*)(xr0 + kc + 36);
    xB[2] = *(const f32x4*)(xr1 + kc + 32);
    xB[3] = *(const f32x4*)(xr1 + kc + 36);
#pragma unroll
    for (int ni = 0; ni < 8; ++ni)
      bB[ni] = *(const half8*)(wp + (size_t)ni * 16 * DI + kc + 32);
    // compute even chunk
    {
      half8 a0, a1;
#pragma unroll
      for (int j = 0; j < 4; ++j) {
        a0[j] = (_Float16)xA[0][j]; a0[4 + j] = (_Float16)xA[1][j];
        a1[j] = (_Float16)xA[2][j]; a1[4 + j] = (_Float16)xA[3][j];
      }
#pragma unroll
      for (int ni = 0; ni < 8; ++ni) {
        acc[0][ni] = __builtin_amdgcn_mfma_f32_16x16x32_f16(a0, bA[ni], acc[0][ni], 0, 0, 0);
        acc[1][ni] = __builtin_amdgcn_mfma_f32_16x16x32_f16(a1, bA[ni], acc[1][ni], 0, 0, 0);
      }
    }
    // prefetch next even chunk
    if (kc + 64 < DI) {
      xA[0] = *(const f32x4*)(xr0 + kc + 64);
      xA[1] = *(const f32x4*)(xr0 + kc + 68);
      xA[2] = *(const f32x4*)(xr1 + kc + 64);
      xA[3] = *(const f32x4*)(xr1 + kc + 68);
#pragma unroll
      for (int ni = 0; ni < 8; ++ni)
        bA[ni] = *(const half8*)(wp + (size_t)ni * 16 * DI + kc + 64);
    }
    // compute odd chunk
    {
      half8 a0, a1;
#pragma unroll
      for (int j = 0; j < 4; ++j) {
        a0[j] = (_Float16)xB[0][j]; a0[4 + j] = (_Float16)xB[1][j];
        a1[j] = (_Float16)xB[2][j]; a1[4 + j] = (_Float16)xB[3][j];
      }
#pragma unroll
      for (int ni = 0; ni < 8; ++ni) {
        acc[0][ni] = __builtin_amdgcn_mfma_f32_16x16x32_f16(a0, bB[ni], acc[0][ni], 0, 0, 0);
        acc[1][ni] = __builtin_amdgcn_mfma_f32_16x16x32_f16(a1, bB[ni], acc[1][ni], 0, 0, 0);
      }
    }
  }
  // C/D: col = lane&15 (+16*ni), row = (lane>>4)*4 + j
#pragma unroll
  for (int mi = 0; mi < 2; ++mi)
#pragma unroll
    for (int ni = 0; ni < 8; ++ni) {
      int col = ni * 16 + lm;
#pragma unroll
      for (int j = 0; j < 4; ++j) {
        int row = m0 + mi * 16 + lk * 4 + j;
        if (row < n) {
          float v = acc[mi][ni][j];
          if (col < 64) p[(size_t)row * 64 + col] = (_Float16)v;
          else q[(size_t)row * 64 + (col - 64)] = (_Float16)(v + bias[col - 64]);
        }
      }
    }
}

// ---------------- small fp16 MFMA GEMM (layers 2-4) ----------------
// wave = 32 rows x NC cols; block = 4 waves = 128 rows. A = h fp16 [n][DIP].
template <int DIP, int NC, int NCR, int DO, int PST>
__global__ __launch_bounds__(256) void gemm_s_kernel(
    const _Float16* __restrict__ h, const _Float16* __restrict__ w16,
    const float* __restrict__ bias, _Float16* __restrict__ p, _Float16* __restrict__ q, int n) {
  constexpr int NF = NC / 16;
  int wave = threadIdx.x >> 6;
  int lane = threadIdx.x & 63;
  int m0 = blockIdx.x * 128 + wave * 32;
  int lm = lane & 15;
  int lk = lane >> 4;
  int r0 = m0 + lm; if (r0 >= n) r0 = n - 1;
  int r1 = m0 + 16 + lm; if (r1 >= n) r1 = n - 1;
  const _Float16* h0 = h + (size_t)r0 * DIP + lk * 8;
  const _Float16* h1 = h + (size_t)r1 * DIP + lk * 8;
  const _Float16* wp = w16 + (size_t)lm * DIP + lk * 8;

  f32x4 acc[2][NF];
#pragma unroll
  for (int mi = 0; mi < 2; ++mi)
#pragma unroll
    for (int ni = 0; ni < NF; ++ni) acc[mi][ni] = (f32x4){0.f, 0.f, 0.f, 0.f};

#pragma unroll
  for (int kc = 0; kc < DIP; kc += 32) {
    half8 a0 = *(const half8*)(h0 + kc);
    half8 a1 = *(const half8*)(h1 + kc);
#pragma unroll
    for (int ni = 0; ni < NF; ++ni) {
      half8 b = *(const half8*)(wp + (size_t)ni * 16 * DIP + kc);
      acc[0][ni] = __builtin_amdgcn_mfma_f32_16x16x32_f16(a0, b, acc[0][ni], 0, 0, 0);
      acc[1][ni] = __builtin_amdgcn_mfma_f32_16x16x32_f16(a1, b, acc[1][ni], 0, 0, 0);
    }
  }
#pragma unroll
  for (int mi = 0; mi < 2; ++mi)
#pragma unroll
    for (int ni = 0; ni < NF; ++ni) {
      int col = ni * 16 + lm;
      if (col >= NCR) continue;
#pragma unroll
      for (int j = 0; j < 4; ++j) {
        int row = m0 + mi * 16 + lk * 4 + j;
        if (row < n) {
          float v = acc[mi][ni][j];
          if (col < DO) p[(size_t)row * PST + col] = (_Float16)v;
          else q[(size_t)row * PST + (col - DO)] = (_Float16)(v + bias[col - DO]);
        }
      }
    }
}

// ---------------- aggregation (fp16 in/out, fp32 accum) ----------------
// PS = p/q row stride in half8 units; HS = h-out row stride in half8 units.
template <int PS, int HS>
__global__ __launch_bounds__(256) void aggregateH_kernel(
    const _Float16* __restrict__ p, const _Float16* __restrict__ q,
    const int* __restrict__ off, const int* __restrict__ csr,
    const float* __restrict__ invd, _Float16* __restrict__ ho, int n) {
  int t = blockIdx.x * 256 + threadIdx.x;
  int node = t / HS;
  int c8 = t - node * HS;
  if (node >= n) return;
  if (c8 >= PS) {  // zero-pad lanes (layer-3 output padded to K=32)
    half8 z = {};
    ((half8*)ho)[(size_t)node * HS + c8] = z;
    return;
  }
  int e0 = off[node], e1 = off[node + 1];
  const half8* p8 = (const half8*)p;
  float s[8];
#pragma unroll
  for (int j = 0; j < 8; ++j) s[j] = 0.f;
  for (int e = e0; e < e1; ++e) {
    half8 v = p8[(size_t)csr[e] * PS + c8];
#pragma unroll
    for (int j = 0; j < 8; ++j) s[j] += (float)v[j];
  }
  float id = invd[node];
  half8 qv = ((const half8*)q)[(size_t)node * PS + c8];
  half8 o;
#pragma unroll
  for (int j = 0; j < 8; ++j) {
    float ov = s[j] * id + (float)qv[j];
    o[j] = (_Float16)fmaxf(ov, 0.f);
  }
  ((half8*)ho)[(size_t)node * HS + c8] = o;
}

// final layer: p,q fp16 [n][8] (cols 0-4 valid), out fp32 [n][5]
__global__ __launch_bounds__(256) void aggregate_last_kernel(
    const _Float16* __restrict__ p, const _Float16* __restrict__ q,
    const int* __restrict__ off, const int* __restrict__ csr,
    const float* __restrict__ invd, float* __restrict__ out, int n) {
  int t = blockIdx.x * 256 + threadIdx.x;
  int node = t >> 3;
  int c = t & 7;
  if (node >= n || c >= 5) return;
  int e0 = off[node], e1 = off[node + 1];
  float s = 0.f;
  for (int e = e0; e < e1; ++e) s += (float)p[(size_t)csr[e] * 8 + c];
  out[(size_t)node * 5 + c] = s * invd[node] + (float)q[(size_t)node * 8 + c];
}

// ---------------- launch ----------------
extern "C" void kernel_launch(void* const* d_in, const int* in_sizes, int n_in,
                              void* d_out, int out_size, void* d_ws, size_t ws_size,
                              hipStream_t stream) {
  const float* x = (const float*)d_in[0];
  const int* ei = (const int*)d_in[1];
  const int E = in_sizes[1] / 2;
  const int* esrc = ei;
  const int* edst = ei + E;
  const float* W1l = (const float*)d_in[3];
  const float* W1r = (const float*)d_in[4];
  const float* b1 = (const float*)d_in[5];
  const float* W2l = (const float*)d_in[6];
  const float* W2r = (const float*)d_in[7];
  const float* b2 = (const float*)d_in[8];
  const float* W3l = (const float*)d_in[9];
  const float* W3r = (const float*)d_in[10];
  const float* b3 = (const float*)d_in[11];
  const float* W4l = (const float*)d_in[12];
  const float* W4r = (const float*)d_in[13];
  const float* b4 = (const float*)d_in[14];
  const int N = in_sizes[0] / 768;
  float* out = (float*)d_out;
  (void)n_in; (void)out_size; (void)ws_size;

  char* base = (char*)d_ws;
  size_t o = 0;
  auto alloc = [&](size_t bytes) -> void* {
    void* ptr = base + o;
    o = (o + bytes + 255) & ~(size_t)255;
    return ptr;
  };
  int* cnt = (int*)alloc((size_t)N * 4);
  int* cur = (int*)alloc((size_t)N * 4);
  int* off = (int*)alloc((size_t)(N + 1) * 4);
  int* bsum = (int*)alloc(1024);
  int* csr = (int*)alloc((size_t)E * 4);
  float* invd = (float*)alloc((size_t)N * 4);
  _Float16* w1 = (_Float16*)alloc((size_t)128 * 768 * 2);
  _Float16* w2 = (_Float16*)alloc((size_t)64 * 64 * 2);
  _Float16* w3 = (_Float16*)alloc((size_t)32 * 32 * 2);
  _Float16* w4 = (_Float16*)alloc((size_t)16 * 32 * 2);
  _Float16* P1 = (_Float16*)alloc((size_t)N * 64 * 2);
  _Float16* Q1 = (_Float16*)alloc((size_t)N * 64 * 2);
  _Float16* H1 = (_Float16*)alloc((size_t)N * 64 * 2);
  _Float16* P2 = (_Float16*)alloc((size_t)N * 32 * 2);
  _Float16* Q2 = (_Float16*)alloc((size_t)N * 32 * 2);
  _Float16* H2 = (_Float16*)alloc((size_t)N * 32 * 2);
  _Float16* P3 = (_Float16*)alloc((size_t)N * 16 * 2);
  _Float16* Q3 = (_Float16*)alloc((size_t)N * 16 * 2);
  _Float16* H3 = (_Float16*)alloc((size_t)N * 32 * 2);  // K-padded to 32
  _Float16* P4 = (_Float16*)alloc((size_t)N * 8 * 2);
  _Float16* Q4 = (_Float16*)alloc((size_t)N * 8 * 2);

  hipMemsetAsync(cnt, 0, (size_t)N * 4, stream);
  hipMemsetAsync(cur, 0, (size_t)N * 4, stream);

  prep_w16_kernel<<<(128 * 768 + 255) / 256, 256, 0, stream>>>(W1l, W1r, w1);
  prep_w16s_kernel<<<(64 * 64 + 255) / 256, 256, 0, stream>>>(W2l, W2r, w2, 64, 64, 32, 64);
  prep_w16s_kernel<<<(32 * 32 + 255) / 256, 256, 0, stream>>>(W3l, W3r, w3, 32, 32, 16, 32);
  prep_w16s_kernel<<<(16 * 32 + 255) / 256, 256, 0, stream>>>(W4l, W4r, w4, 16, 32, 5, 16);

  deg_kernel<<<(E + 255) / 256, 256, 0, stream>>>(edst, cnt, E);
  invdeg_kernel<<<(N + 255) / 256, 256, 0, stream>>>(cnt, invd, N);
  const int nb = (N + 1 + 1023) / 1024;
  scan1_kernel<<<nb, 256, 0, stream>>>(cnt, off, bsum, N);
  scan2_kernel<<<1, 128, 0, stream>>>(bsum, nb);
  scan3_kernel<<<(N + 1 + 255) / 256, 256, 0, stream>>>(off, bsum, N + 1);
  sortfill_kernel<<<(E + 255) / 256, 256, 0, stream>>>(esrc, edst, off, cur, csr, E);

  const int gb = (N + 127) / 128;
  // Layer 1: 768 -> 64
  gemm1_mfma_kernel<<<(N + 31) / 32, 64, 0, stream>>>(x, w1, b1, P1, Q1, N);
  aggregateH_kernel<8, 8><<<(N * 8 + 255) / 256, 256, 0, stream>>>(P1, Q1, off, csr, invd, H1, N);
  // Layer 2: 64 -> 32
  gemm_s_kernel<64, 64, 64, 32, 32><<<gb, 256, 0, stream>>>(H1, w2, b2, P2, Q2, N);
  aggregateH_kernel<4, 4><<<(N * 4 + 255) / 256, 256, 0, stream>>>(P2, Q2, off, csr, invd, H2, N);
  // Layer 3: 32 -> 16 (H3 padded to 32 k)
  gemm_s_kernel<32, 32, 32, 16, 16><<<gb, 256, 0, stream>>>(H2, w3, b3, P3, Q3, N);
  aggregateH_kernel<2, 4><<<(N * 4 + 255) / 256, 256, 0, stream>>>(P3, Q3, off, csr, invd, H3, N);
  // Layer 4: 16(pad 32) -> 5
  gemm_s_kernel<32, 16, 10, 5, 8><<<gb, 256, 0, stream>>>(H3, w4, b4, P4, Q4, N);
  aggregate_last_kernel<<<(N * 8 + 255) / 256, 256, 0, stream>>>(P4, Q4, off, csr, invd, out, N);
}

// Round 4
// 314.974 us; speedup vs baseline: 2.5459x; 1.0870x over previous
//
#include <hip/hip_runtime.h>

using half8 = __attribute__((ext_vector_type(8))) _Float16;
using f32x4 = __attribute__((ext_vector_type(4))) float;

typedef __attribute__((address_space(3))) unsigned int lds_uint;
typedef __attribute__((address_space(1))) const unsigned int glb_uint;
__device__ __forceinline__ void async_copy16(const void* g, void* l) {
  __builtin_amdgcn_global_load_lds((glb_uint*)g, (lds_uint*)l, 16, 0, 0);
}

// ---------------- prep: all 4 layers' weights -> fp16, one kernel ----------------
// w1 [128][768]; w2 [64][64]; w3 [32][32]; w4 [16][32] (k-padded 16->32, col-padded 10->16)
__global__ void prep_all_kernel(const float* __restrict__ W1l, const float* __restrict__ W1r,
                                const float* __restrict__ W2l, const float* __restrict__ W2r,
                                const float* __restrict__ W3l, const float* __restrict__ W3r,
                                const float* __restrict__ W4l, const float* __restrict__ W4r,
                                _Float16* __restrict__ w1, _Float16* __restrict__ w2,
                                _Float16* __restrict__ w3, _Float16* __restrict__ w4) {
  int i = blockIdx.x * 256 + threadIdx.x;
  if (i < 98304) {  // 128*768
    int c = i / 768, k = i - c * 768;
    float v = (c < 64) ? W1l[k * 64 + c] : W1r[k * 64 + (c - 64)];
    w1[i] = (_Float16)v;
  } else if (i < 98304 + 4096) {  // w2: [64][64]
    int j = i - 98304;
    int c = j >> 6, k = j & 63;
    float v = (c < 32) ? W2l[k * 32 + c] : W2r[k * 32 + (c - 32)];
    w2[j] = (_Float16)v;
  } else if (i < 98304 + 4096 + 1024) {  // w3: [32][32]
    int j = i - (98304 + 4096);
    int c = j >> 5, k = j & 31;
    float v = (c < 16) ? W3l[k * 16 + c] : W3r[k * 16 + (c - 16)];
    w3[j] = (_Float16)v;
  } else if (i < 98304 + 4096 + 1024 + 512) {  // w4: [16][32], k<16 real, c<10 real
    int j = i - (98304 + 4096 + 1024);
    int c = j >> 5, k = j & 31;
    float v = 0.f;
    if (k < 16) {
      if (c < 5) v = W4l[k * 5 + c];
      else if (c < 10) v = W4r[k * 5 + (c - 5)];
    }
    w4[j] = (_Float16)v;
  }
}

// ---------------- CSR build ----------------
__global__ void deg_kernel(const int* __restrict__ dst, int* __restrict__ cnt, int e) {
  int i = blockIdx.x * 256 + threadIdx.x;
  if (i < e) atomicAdd(&cnt[dst[i]], 1);
}

// exclusive scan pass 1 (+ inv_deg fused)
__global__ void scan1_kernel(const int* __restrict__ cnt, int* __restrict__ off,
                             int* __restrict__ bsum, float* __restrict__ invd, int nodes) {
  __shared__ int sh[256];
  int tid = threadIdx.x;
  int base = blockIdx.x * 1024 + tid * 4;
  int a0 = (base + 0 < nodes) ? cnt[base + 0] : 0;
  int a1 = (base + 1 < nodes) ? cnt[base + 1] : 0;
  int a2 = (base + 2 < nodes) ? cnt[base + 2] : 0;
  int a3 = (base + 3 < nodes) ? cnt[base + 3] : 0;
  if (base + 0 < nodes) invd[base + 0] = a0 > 0 ? 1.0f / (float)a0 : 0.f;
  if (base + 1 < nodes) invd[base + 1] = a1 > 0 ? 1.0f / (float)a1 : 0.f;
  if (base + 2 < nodes) invd[base + 2] = a2 > 0 ? 1.0f / (float)a2 : 0.f;
  if (base + 3 < nodes) invd[base + 3] = a3 > 0 ? 1.0f / (float)a3 : 0.f;
  int s3 = a0 + a1 + a2 + a3;
  sh[tid] = s3;
  __syncthreads();
  for (int d = 1; d < 256; d <<= 1) {
    int v = (tid >= d) ? sh[tid - d] : 0;
    __syncthreads();
    sh[tid] += v;
    __syncthreads();
  }
  int excl = sh[tid] - s3;
  if (base + 0 <= nodes) off[base + 0] = excl;
  if (base + 1 <= nodes) off[base + 1] = excl + a0;
  if (base + 2 <= nodes) off[base + 2] = excl + a0 + a1;
  if (base + 3 <= nodes) off[base + 3] = excl + a0 + a1 + a2;
  if (tid == 255) bsum[blockIdx.x] = sh[255];
}

__global__ void scan2_kernel(int* __restrict__ bsum, int nb) {
  __shared__ int sh[128];
  int tid = threadIdx.x;
  int v = (tid < nb) ? bsum[tid] : 0;
  sh[tid] = v;
  __syncthreads();
  for (int d = 1; d < 128; d <<= 1) {
    int u = (tid >= d) ? sh[tid - d] : 0;
    __syncthreads();
    sh[tid] += u;
    __syncthreads();
  }
  if (tid < nb) bsum[tid] = sh[tid] - v;
}

__global__ void scan3_kernel(int* __restrict__ off, const int* __restrict__ bsum, int ntot) {
  int i = blockIdx.x * 256 + threadIdx.x;
  if (i < ntot) off[i] += bsum[i >> 10];
}

__global__ void sortfill_kernel(const int* __restrict__ src, const int* __restrict__ dst,
                                const int* __restrict__ off, int* __restrict__ cur,
                                int* __restrict__ csr, int e) {
  int i = blockIdx.x * 256 + threadIdx.x;
  if (i < e) {
    int d = dst[i];
    int pos = atomicAdd(&cur[d], 1);
    csr[off[d] + pos] = src[i];
  }
}

// ---------------- layer-1 MFMA GEMM with global_load_lds staging ----------------
// Block: 256 thr (4 waves), tile 128 rows x 128 cols, BK=64 fp32, LDS 2x32KB dbuf.
// XOR swizzle: LDS[r][byte] = x[r][byte ^ ((r&7)<<4)]  (applied on global source).
__global__ __launch_bounds__(256, 2) void gemm1_kernel(
    const float* __restrict__ x,       // [n][768]
    const _Float16* __restrict__ w16,  // [128][768]
    const float* __restrict__ bias,    // [64]
    _Float16* __restrict__ p, _Float16* __restrict__ q, int n) {
  constexpr int DI = 768, BK = 64, NT = DI / BK;
  __shared__ float xs[2][128 * BK];  // 2 x 32 KB
  int t = threadIdx.x;
  int lane = t & 63, w = t >> 6;
  int lm = lane & 15, lk = lane >> 4;
  int m0 = blockIdx.x * 128;

  // staging: thread covers 8 x 16B; wave chunk j at lds float off (j*4+w)*256
  const float* gp[8];
  int jbase[8];
#pragma unroll
  for (int j = 0; j < 8; ++j) {
    int row = (j * 4 + w) * 4 + (lane >> 4);
    int g = (lane & 15) ^ (row & 7);  // 16B-granule index after inverse swizzle
    int grow = m0 + row;
    if (grow >= n) grow = n - 1;
    gp[j] = x + (size_t)grow * DI + g * 4;
    jbase[j] = (j * 4 + w) * 256;
  }

  f32x4 acc[2][8];
#pragma unroll
  for (int mi = 0; mi < 2; ++mi)
#pragma unroll
    for (int ni = 0; ni < 8; ++ni) acc[mi][ni] = (f32x4){0.f, 0.f, 0.f, 0.f};

  // prologue: stage tile 0
#pragma unroll
  for (int j = 0; j < 8; ++j) async_copy16(gp[j], &xs[0][jbase[j]]);
  asm volatile("s_waitcnt vmcnt(0)" ::: "memory");
  __syncthreads();

  int r0l = w * 32 + lm, r1l = r0l + 16;
  const _Float16* wp = w16 + (size_t)lm * DI + lk * 8;

  for (int ts = 0; ts < NT; ++ts) {
    int cur = ts & 1;
    if (ts + 1 < NT) {
      int kc = (ts + 1) * BK;
#pragma unroll
      for (int j = 0; j < 8; ++j) async_copy16(gp[j] + kc, &xs[cur ^ 1][jbase[j]]);
    }
    const float* xb = xs[cur];
    int kc0 = ts * BK;
#pragma unroll
    for (int s = 0; s < 2; ++s) {
      // swizzled fragment reads: float off = r*64 + (((s*8+lk*2+h) ^ (r&7)) << 2)
      f32x4 v0a = *(const f32x4*)(xb + r0l * 64 + ((((s << 3) + (lk << 1) + 0) ^ (r0l & 7)) << 2));
      f32x4 v0b = *(const f32x4*)(xb + r0l * 64 + ((((s << 3) + (lk << 1) + 1) ^ (r0l & 7)) << 2));
      f32x4 v1a = *(const f32x4*)(xb + r1l * 64 + ((((s << 3) + (lk << 1) + 0) ^ (r1l & 7)) << 2));
      f32x4 v1b = *(const f32x4*)(xb + r1l * 64 + ((((s << 3) + (lk << 1) + 1) ^ (r1l & 7)) << 2));
      half8 a0, a1;
#pragma unroll
      for (int j = 0; j < 4; ++j) {
        a0[j] = (_Float16)v0a[j]; a0[4 + j] = (_Float16)v0b[j];
        a1[j] = (_Float16)v1a[j]; a1[4 + j] = (_Float16)v1b[j];
      }
#pragma unroll
      for (int ni = 0; ni < 8; ++ni) {
        half8 b = *(const half8*)(wp + (size_t)ni * 16 * DI + kc0 + s * 32);
        acc[0][ni] = __builtin_amdgcn_mfma_f32_16x16x32_f16(a0, b, acc[0][ni], 0, 0, 0);
        acc[1][ni] = __builtin_amdgcn_mfma_f32_16x16x32_f16(a1, b, acc[1][ni], 0, 0, 0);
      }
    }
    asm volatile("s_waitcnt vmcnt(0)" ::: "memory");
    __syncthreads();
  }

  // C/D: col = ni*16 + lm, row = m0 + w*32 + mi*16 + lk*4 + j
#pragma unroll
  for (int mi = 0; mi < 2; ++mi)
#pragma unroll
    for (int ni = 0; ni < 8; ++ni) {
      int col = ni * 16 + lm;
#pragma unroll
      for (int j = 0; j < 4; ++j) {
        int row = m0 + w * 32 + mi * 16 + lk * 4 + j;
        if (row < n) {
          float v = acc[mi][ni][j];
          if (col < 64) p[(size_t)row * 64 + col] = (_Float16)v;
          else q[(size_t)row * 64 + (col - 64)] = (_Float16)(v + bias[col - 64]);
        }
      }
    }
}

// ---------------- fused aggregate(+relu) -> gemm for layers 2-4 ----------------
// Phase A: 2 threads/node aggregate h=relu(mean(pin[src])+qin) into LDS [128][SP].
// Phase B: 4 waves x 32 rows x NC cols MFMA from LDS, write pout/qout fp16.
template <int DIR, int DIP, int PSI, int NC, int NCR, int DO, int PSO>
__global__ __launch_bounds__(256) void fused_agg_gemm_kernel(
    const _Float16* __restrict__ pin, const _Float16* __restrict__ qin,
    const int* __restrict__ off, const int* __restrict__ csr, const float* __restrict__ invd,
    const _Float16* __restrict__ w16, const float* __restrict__ bias,
    _Float16* __restrict__ pout, _Float16* __restrict__ qout, int n) {
  constexpr int SP = DIP + 8;   // LDS row stride (fp16): bank-staggered
  constexpr int C8 = DIR / 8;   // real half8 chunks per node
  constexpr int CT = C8 / 2;    // chunks per thread (2 threads/node)
  constexpr int NF = NC / 16;
  __shared__ _Float16 hs[128 * SP];
  int t = threadIdx.x;
  int node_l = t >> 1, half = t & 1;
  int node = blockIdx.x * 128 + node_l;

  if (node < n) {
    int e0 = off[node], e1 = off[node + 1];
    const half8* p8 = (const half8*)pin;
    float s[CT][8];
#pragma unroll
    for (int c = 0; c < CT; ++c)
#pragma unroll
      for (int j = 0; j < 8; ++j) s[c][j] = 0.f;
    for (int e = e0; e < e1; ++e) {
      int src = csr[e];
#pragma unroll
      for (int c = 0; c < CT; ++c) {
        half8 v = p8[(size_t)src * PSI + half * CT + c];
#pragma unroll
        for (int j = 0; j < 8; ++j) s[c][j] += (float)v[j];
      }
    }
    float id = invd[node];
#pragma unroll
    for (int c = 0; c < CT; ++c) {
      half8 qv = ((const half8*)qin)[(size_t)node * PSI + half * CT + c];
      half8 o;
#pragma unroll
      for (int j = 0; j < 8; ++j) o[j] = (_Float16)fmaxf(s[c][j] * id + (float)qv[j], 0.f);
      *(half8*)(hs + node_l * SP + (half * CT + c) * 8) = o;
    }
    if (DIP > DIR) {  // zero-pad k (layer 4)
      half8 z = {};
      *(half8*)(hs + node_l * SP + (C8 + half) * 8) = z;
    }
  }
  __syncthreads();

  // Phase B
  int lane = t & 63, w = t >> 6;
  int lm = lane & 15, lk = lane >> 4;
  int r0l = w * 32 + lm, r1l = r0l + 16;
  const _Float16* wp = w16 + (size_t)lm * DIP + lk * 8;
  f32x4 acc[2][NF];
#pragma unroll
  for (int mi = 0; mi < 2; ++mi)
#pragma unroll
    for (int ni = 0; ni < NF; ++ni) acc[mi][ni] = (f32x4){0.f, 0.f, 0.f, 0.f};
#pragma unroll
  for (int kc = 0; kc < DIP; kc += 32) {
    half8 a0 = *(const half8*)(hs + r0l * SP + kc + lk * 8);
    half8 a1 = *(const half8*)(hs + r1l * SP + kc + lk * 8);
#pragma unroll
    for (int ni = 0; ni < NF; ++ni) {
      half8 b = *(const half8*)(wp + (size_t)ni * 16 * DIP + kc);
      acc[0][ni] = __builtin_amdgcn_mfma_f32_16x16x32_f16(a0, b, acc[0][ni], 0, 0, 0);
      acc[1][ni] = __builtin_amdgcn_mfma_f32_16x16x32_f16(a1, b, acc[1][ni], 0, 0, 0);
    }
  }
#pragma unroll
  for (int mi = 0; mi < 2; ++mi)
#pragma unroll
    for (int ni = 0; ni < NF; ++ni) {
      int col = ni * 16 + lm;
      if (col >= NCR) continue;
#pragma unroll
      for (int j = 0; j < 4; ++j) {
        int row = blockIdx.x * 128 + w * 32 + mi * 16 + lk * 4 + j;
        if (row < n) {
          float v = acc[mi][ni][j];
          if (col < DO) pout[(size_t)row * PSO + col] = (_Float16)v;
          else qout[(size_t)row * PSO + (col - DO)] = (_Float16)(v + bias[col - DO]);
        }
      }
    }
}

// final aggregation: p,q fp16 [n][8] (cols 0-4 valid), out fp32 [n][5]
__global__ __launch_bounds__(256) void aggregate_last_kernel(
    const _Float16* __restrict__ p, const _Float16* __restrict__ q,
    const int* __restrict__ off, const int* __restrict__ csr,
    const float* __restrict__ invd, float* __restrict__ out, int n) {
  int t = blockIdx.x * 256 + threadIdx.x;
  int node = t >> 3;
  int c = t & 7;
  if (node >= n || c >= 5) return;
  int e0 = off[node], e1 = off[node + 1];
  float s = 0.f;
  for (int e = e0; e < e1; ++e) s += (float)p[(size_t)csr[e] * 8 + c];
  out[(size_t)node * 5 + c] = s * invd[node] + (float)q[(size_t)node * 8 + c];
}

// ---------------- launch ----------------
extern "C" void kernel_launch(void* const* d_in, const int* in_sizes, int n_in,
                              void* d_out, int out_size, void* d_ws, size_t ws_size,
                              hipStream_t stream) {
  const float* x = (const float*)d_in[0];
  const int* ei = (const int*)d_in[1];
  const int E = in_sizes[1] / 2;
  const int* esrc = ei;
  const int* edst = ei + E;
  const float* W1l = (const float*)d_in[3];
  const float* W1r = (const float*)d_in[4];
  const float* b1 = (const float*)d_in[5];
  const float* W2l = (const float*)d_in[6];
  const float* W2r = (const float*)d_in[7];
  const float* b2 = (const float*)d_in[8];
  const float* W3l = (const float*)d_in[9];
  const float* W3r = (const float*)d_in[10];
  const float* b3 = (const float*)d_in[11];
  const float* W4l = (const float*)d_in[12];
  const float* W4r = (const float*)d_in[13];
  const float* b4 = (const float*)d_in[14];
  const int N = in_sizes[0] / 768;
  float* out = (float*)d_out;
  (void)n_in; (void)out_size; (void)ws_size;

  char* base = (char*)d_ws;
  size_t o = 0;
  auto alloc = [&](size_t bytes) -> void* {
    void* ptr = base + o;
    o = (o + bytes + 255) & ~(size_t)255;
    return ptr;
  };
  int* cnt = (int*)alloc((size_t)2 * N * 4);  // cnt + cur contiguous
  int* cur = cnt + N;
  int* off = (int*)alloc((size_t)(N + 1) * 4);
  int* bsum = (int*)alloc(1024);
  int* csr = (int*)alloc((size_t)E * 4);
  float* invd = (float*)alloc((size_t)N * 4);
  _Float16* w1 = (_Float16*)alloc((size_t)128 * 768 * 2);
  _Float16* w2 = (_Float16*)alloc((size_t)64 * 64 * 2);
  _Float16* w3 = (_Float16*)alloc((size_t)32 * 32 * 2);
  _Float16* w4 = (_Float16*)alloc((size_t)16 * 32 * 2);
  _Float16* P1 = (_Float16*)alloc((size_t)N * 64 * 2);
  _Float16* Q1 = (_Float16*)alloc((size_t)N * 64 * 2);
  _Float16* P2 = (_Float16*)alloc((size_t)N * 32 * 2);
  _Float16* Q2 = (_Float16*)alloc((size_t)N * 32 * 2);
  _Float16* P3 = (_Float16*)alloc((size_t)N * 16 * 2);
  _Float16* Q3 = (_Float16*)alloc((size_t)N * 16 * 2);
  _Float16* P4 = (_Float16*)alloc((size_t)N * 8 * 2);
  _Float16* Q4 = (_Float16*)alloc((size_t)N * 8 * 2);

  hipMemsetAsync(cnt, 0, (size_t)2 * N * 4, stream);
  prep_all_kernel<<<(98304 + 4096 + 1024 + 512 + 255) / 256, 256, 0, stream>>>(
      W1l, W1r, W2l, W2r, W3l, W3r, W4l, W4r, w1, w2, w3, w4);

  deg_kernel<<<(E + 255) / 256, 256, 0, stream>>>(edst, cnt, E);
  const int nb = (N + 1 + 1023) / 1024;
  scan1_kernel<<<nb, 256, 0, stream>>>(cnt, off, bsum, invd, N);
  scan2_kernel<<<1, 128, 0, stream>>>(bsum, nb);
  scan3_kernel<<<(N + 1 + 255) / 256, 256, 0, stream>>>(off, bsum, N + 1);
  sortfill_kernel<<<(E + 255) / 256, 256, 0, stream>>>(esrc, edst, off, cur, csr, E);

  const int gb = (N + 127) / 128;
  // Layer 1: 768 -> 64 (LDS-staged MFMA)
  gemm1_kernel<<<gb, 256, 0, stream>>>(x, w1, b1, P1, Q1, N);
  // Layers 2-4 fused with preceding aggregation
  fused_agg_gemm_kernel<64, 64, 8, 64, 64, 32, 32>
      <<<gb, 256, 0, stream>>>(P1, Q1, off, csr, invd, w2, b2, P2, Q2, N);
  fused_agg_gemm_kernel<32, 32, 4, 32, 32, 16, 16>
      <<<gb, 256, 0, stream>>>(P2, Q2, off, csr, invd, w3, b3, P3, Q3, N);
  fused_agg_gemm_kernel<16, 32, 2, 16, 10, 5, 8>
      <<<gb, 256, 0, stream>>>(P3, Q3, off, csr, invd, w4, b4, P4, Q4, N);
  aggregate_last_kernel<<<(N * 8 + 255) / 256, 256, 0, stream>>>(P4, Q4, off, csr, invd, out, N);
}